// Round 1
// baseline (126.376 us; speedup 1.0000x reference)
//
#include <hip/hip_runtime.h>
#include <math.h>

// Problem constants (match reference)
#define T36   36
#define NPOLE 161
#define K645  645   // 4*161 + 1 dictionary columns
#define KH    37    // compressed dim: 36 (span of D^T) + 1 (all-ones direction)
#define NITER 40
#define GAMMA_C 0.05

// ---------------------------------------------------------------------------
// ws layout (as doubles from base):
//   Dt   [645][36]  @ 0        (23220)
//   G36  [36][36]   @ 23220    (1296)
//   d1   [36]       @ 24516    (36)
//   scal [2]        @ 24552    (linv, lambd)
//   H    [37][37]   @ 24554    (1369)
//   Ufin [37][37]   @ 25923    (1369)
//   Mf (float)[645][37] @ double-offset 27292  (95460 B)
// total ~314 KB
// ---------------------------------------------------------------------------

// K1: build normalized dictionary, stored transposed: Dt[k][i] = dic[i][k]/G[k]
__global__ void k_build_dict(const float* __restrict__ rr, const float* __restrict__ theta,
                             double* __restrict__ Dt) {
    int k = blockIdx.x * blockDim.x + threadIdx.x;
    if (k >= K645) return;
    if (k == 0) {  // ones column, norm sqrt(36)=6
        const double inv = 1.0 / 6.0;
        for (int i = 0; i < T36; ++i) Dt[i] = inv;
        return;
    }
    int g = (k - 1) / NPOLE;      // 0: r^i c, 1: (-r)^i c, 2: r^i s, 3: (-r)^i s
    int p = (k - 1) % NPOLE;
    double r  = (double)rr[p];
    double th = (double)theta[p];
    bool alt     = (g == 1) || (g == 3);
    bool use_sin = (g >= 2);
    double ss = 0.0, rp = 1.0;
    for (int i = 0; i < T36; ++i) {
        double s, c;
        sincos(th * (double)i, &s, &c);
        double v = rp * (use_sin ? s : c);
        if (alt && (i & 1)) v = -v;
        ss += v * v;
        rp *= r;
    }
    double gn = sqrt(ss);
    if (gn == 0.0) gn = 6.0;      // reference: G==0 -> sqrt(T)
    double inv = 1.0 / gn;
    rp = 1.0;
    for (int i = 0; i < T36; ++i) {
        double s, c;
        sincos(th * (double)i, &s, &c);
        double v = rp * (use_sin ? s : c);
        if (alt && (i & 1)) v = -v;
        Dt[k * T36 + i] = v * inv;
        rp *= r;
    }
}

// K2: G36[a][b] = sum_k Dt[k][a]*Dt[k][b]  (b==36 -> d1[a] = sum_k Dt[k][a])
__global__ void k_gram(const double* __restrict__ Dt, double* __restrict__ G36,
                       double* __restrict__ d1v) {
    int a = blockIdx.x;           // 0..35
    int b = blockIdx.y;           // 0..36
    int lane = threadIdx.x;       // 64 = one wave
    double acc = 0.0;
    if (b < T36) {
        for (int k = lane; k < K645; k += 64) acc += Dt[k * T36 + a] * Dt[k * T36 + b];
    } else {
        for (int k = lane; k < K645; k += 64) acc += Dt[k * T36 + a];
    }
    for (int off = 32; off > 0; off >>= 1) acc += __shfl_down(acc, off);
    if (lane == 0) {
        if (b < T36) G36[a * T36 + b] = acc;
        else         d1v[a] = acc;
    }
}

// K3: L = ||G36||_F (== ||D^T D||_F), linv, lambd; build compressed operator H[37][37]
__global__ void k_finalize(const double* __restrict__ G36, const double* __restrict__ d1v,
                           double* __restrict__ scal, double* __restrict__ H) {
    int tid = threadIdx.x;        // 1024
    double s = 0.0;
    for (int i = tid; i < T36 * T36; i += 1024) { double v = G36[i]; s += v * v; }
    for (int off = 32; off > 0; off >>= 1) s += __shfl_down(s, off);
    __shared__ double wsum[16];
    __shared__ double sc[2];
    if ((tid & 63) == 0) wsum[tid >> 6] = s;
    __syncthreads();
    if (tid == 0) {
        double tot = 0.0;
        for (int w = 0; w < 16; ++w) tot += wsum[w];
        double L = sqrt(tot);
        double linv = (L == 0.0) ? 0.0 : 1.0 / L;
        sc[0] = linv;
        sc[1] = GAMMA_C * linv;   // lambd
        scal[0] = sc[0];
        scal[1] = sc[1];
    }
    __syncthreads();
    double linv = sc[0];
    // H: rows 0..35: I - linv*[G36 | d1]; row 36: e36^T (ones-direction passthrough)
    for (int idx = tid; idx < KH * KH; idx += 1024) {
        int a = idx / KH, q = idx % KH;
        double h;
        if (a < T36) h = ((a == q) ? 1.0 : 0.0) - linv * ((q < T36) ? G36[a * T36 + q] : d1v[a]);
        else         h = (q == T36) ? 1.0 : 0.0;
        H[idx] = h;
    }
}

// K4: 40 FISTA iterations on the compressed 37x37 state. Columns are independent:
// one block (one wave) per column t. Uhat_x = H*Uhat_y + Ehat; momentum elementwise.
__global__ void k_iterate(const double* __restrict__ H, const double* __restrict__ scal,
                          double* __restrict__ Ufin) {
    int t = blockIdx.x;           // 0..36 (column of compressed state)
    int lane = threadIdx.x;       // 64
    __shared__ double yl[KH];
    double Hreg[KH];
    double Eh = 0.0, xold = 0.0;
    double linv = scal[0], lambd = scal[1];
    if (lane < KH) {
#pragma unroll
        for (int q = 0; q < KH; ++q) Hreg[q] = H[lane * KH + q];
        // Ehat[a][t]: rows<36: linv*delta(a,t) (t<36); row 36: -lambd at t==36
        Eh = (lane < T36) ? ((lane == t && t < T36) ? linv : 0.0)
                          : ((t == T36) ? -lambd : 0.0);
        yl[lane] = 0.0;
    } else {
#pragma unroll
        for (int q = 0; q < KH; ++q) Hreg[q] = 0.0;
    }
    __syncthreads();
    double tcur = 1.0;
    for (int n = 0; n < NITER; ++n) {
        // momentum coefficient, bit-matching reference's float32 tts
        double tn = 0.5 * (1.0 + sqrt(1.0 + 4.0 * tcur * tcur));
        double tt = (double)(float)((tcur - 1.0) / tn);
        tcur = tn;
        double acc = Eh;
#pragma unroll
        for (int q = 0; q < KH; ++q) acc += Hreg[q] * yl[q];   // x_new = H*y + E
        __syncthreads();
        double ynew = (1.0 + tt) * acc - tt * xold;
        xold = acc;
        if (lane < KH) yl[lane] = ynew;
        __syncthreads();
    }
    if (lane < KH) Ufin[lane * KH + t] = xold;   // x_40 compressed
}

// K5: expand: Mf[k][t] = sum_s Dt[k][s]*Ufin[s][t] + Ufin[36][t]  (fp32 out)
__global__ void k_expand(const double* __restrict__ Dt, const double* __restrict__ Ufin,
                         float* __restrict__ Mf) {
    int idx = blockIdx.x * 256 + threadIdx.x;
    if (idx >= K645 * KH) return;
    int k = idx / KH, t = idx % KH;
    double acc = Ufin[T36 * KH + t];
#pragma unroll
    for (int q = 0; q < T36; ++q) acc += Dt[k * T36 + q] * Ufin[q * KH + t];
    Mf[idx] = (float)acc;
}

// K6: out[k][p] = sum_t Mf[k][t]*Y[t][p] + Mf[k][36]
__global__ __launch_bounds__(256) void k_out(const float* __restrict__ Y,
                                             const float* __restrict__ Mf,
                                             float* __restrict__ out, int P) {
    int p = blockIdx.x * 256 + threadIdx.x;
    if (p >= P) return;
    int k0 = blockIdx.y * 15;     // 43 chunks * 15 = 645
    float y[T36];
#pragma unroll
    for (int t = 0; t < T36; ++t) y[t] = Y[t * P + p];
    for (int kk = 0; kk < 15; ++kk) {
        int k = k0 + kk;
        const float* m = Mf + k * KH;   // uniform across block -> scalar loads
        float acc = m[T36];
#pragma unroll
        for (int t = 0; t < T36; ++t) acc = fmaf(m[t], y[t], acc);
        out[k * P + p] = acc;
    }
}

extern "C" void kernel_launch(void* const* d_in, const int* in_sizes, int n_in,
                              void* d_out, int out_size, void* d_ws, size_t ws_size,
                              hipStream_t stream) {
    const float* x     = (const float*)d_in[0];   // [1, 36, 8192]
    const float* rr    = (const float*)d_in[1];   // [161]
    const float* theta = (const float*)d_in[2];   // [161]
    float* out = (float*)d_out;                   // [1, 645, 8192]

    double* ws   = (double*)d_ws;                 // needs ~314 KB
    double* Dt   = ws;                            // 23220
    double* G36  = ws + 23220;                    // 1296
    double* d1v  = ws + 24516;                    // 36
    double* scal = ws + 24552;                    // 2
    double* H    = ws + 24554;                    // 1369
    double* Ufin = ws + 25923;                    // 1369
    float*  Mf   = (float*)(ws + 27292);          // 645*37 floats

    int P = in_sizes[0] / T36;                    // 8192

    k_build_dict<<<dim3((K645 + 255) / 256), dim3(256), 0, stream>>>(rr, theta, Dt);
    k_gram<<<dim3(T36, KH), dim3(64), 0, stream>>>(Dt, G36, d1v);
    k_finalize<<<dim3(1), dim3(1024), 0, stream>>>(G36, d1v, scal, H);
    k_iterate<<<dim3(KH), dim3(64), 0, stream>>>(H, scal, Ufin);
    k_expand<<<dim3((K645 * KH + 255) / 256), dim3(256), 0, stream>>>(Dt, Ufin, Mf);
    k_out<<<dim3((P + 255) / 256, 43), dim3(256), 0, stream>>>(x, Mf, out, P);
}

// Round 2
// 110.415 us; speedup vs baseline: 1.1446x; 1.1446x over previous
//
#include <hip/hip_runtime.h>
#include <math.h>

// Problem constants (match reference)
#define T36   36
#define NPOLE 161
#define K645  645   // 4*161 + 1 dictionary columns
#define KH    37    // compressed dim: 36 (span of D^T) + 1 (ones direction)
#define NITER 40
#define GAMMA_C 0.05

// ---------------------------------------------------------------------------
// ws layout (as doubles from base):
//   Di   [36][645]  @ 0        (23220)   dictionary, i-major, normalized
//   G36  [36][36]   @ 23220    (1296)
//   d1   [36]       @ 24516    (36)
//   Mf (float)[645][37] @ double-offset 24552  (95460 B)
// total ~292 KB
// ---------------------------------------------------------------------------

// K1: build normalized dictionary via sincos recurrence.
// Di[i][k] = dic[i][k] / ||dic[:,k]||  (i-major layout for coalesced gram reads)
__global__ void k_build(const float* __restrict__ rr, const float* __restrict__ theta,
                        double* __restrict__ Di) {
    int k = blockIdx.x * blockDim.x + threadIdx.x;
    if (k >= K645) return;
    if (k == 0) {  // ones column, norm sqrt(36)=6
        const double inv = 1.0 / 6.0;
#pragma unroll
        for (int i = 0; i < T36; ++i) Di[i * K645] = inv;
        return;
    }
    int g = (k - 1) / NPOLE;      // 0: r^i c, 1: (-r)^i c, 2: r^i s, 3: (-r)^i s
    int p = (k - 1) % NPOLE;
    double r  = (double)rr[p];
    double th = (double)theta[p];
    bool alt     = (g == 1) || (g == 3);
    bool use_sin = (g >= 2);
    double sth, cth;
    sincos(th, &sth, &cth);       // ONE transcendental; rest is rotation recurrence
    double ci = 1.0, si = 0.0, rp = 1.0, ss = 0.0;
    double val[T36];
#pragma unroll
    for (int i = 0; i < T36; ++i) {
        double v = rp * (use_sin ? si : ci);
        if (alt && (i & 1)) v = -v;
        val[i] = v;
        ss += v * v;
        double cn = ci * cth - si * sth;
        double sn = si * cth + ci * sth;
        ci = cn; si = sn; rp *= r;
    }
    double gn = sqrt(ss);
    if (gn == 0.0) gn = 6.0;      // reference: G==0 -> sqrt(T)
    double inv = 1.0 / gn;
#pragma unroll
    for (int i = 0; i < T36; ++i) Di[i * K645 + k] = val[i] * inv;
}

// K2: G36[a][b] = sum_k Di[a][k]*Di[b][k]  (b==36 -> d1[a] = sum_k Di[a][k])
// Rows are contiguous -> coalesced.
__global__ __launch_bounds__(64) void k_gram(const double* __restrict__ Di,
                                             double* __restrict__ G36,
                                             double* __restrict__ d1v) {
    int a = blockIdx.x;           // 0..35
    int b = blockIdx.y;           // 0..36
    int lane = threadIdx.x;       // one wave
    const double* Da = Di + a * K645;
    double acc = 0.0;
    if (b < T36) {
        const double* Db = Di + b * K645;
        for (int k = lane; k < K645; k += 64) acc += Da[k] * Db[k];
    } else {
        for (int k = lane; k < K645; k += 64) acc += Da[k];
    }
#pragma unroll
    for (int off = 32; off > 0; off >>= 1) acc += __shfl_down(acc, off);
    if (lane == 0) {
        if (b < T36) G36[a * T36 + b] = acc;
        else         d1v[a] = acc;
    }
}

// K3 (fused finalize+iterate+expand): one block (one wave) per compressed column t.
// Each block redundantly computes L = ||G36||_F, builds its H rows in registers,
// runs the 40-step linear FISTA recurrence on the 37-vector, then expands its
// own column into Mf[k][t] = sum_s Di[s][k]*x[s] + x[36].
__global__ __launch_bounds__(64) void k_solve(const double* __restrict__ Di,
                                              const double* __restrict__ G36,
                                              const double* __restrict__ d1v,
                                              float* __restrict__ Mf) {
    int t = blockIdx.x;           // 0..36
    int lane = threadIdx.x;       // 64
    // Frobenius norm of G36 (== ||D^T D||_F), broadcast to all lanes
    double s = 0.0;
    for (int i = lane; i < T36 * T36; i += 64) { double v = G36[i]; s += v * v; }
#pragma unroll
    for (int off = 32; off > 0; off >>= 1) s += __shfl_xor(s, off);
    double L = sqrt(s);
    double linv = (L == 0.0) ? 0.0 : 1.0 / L;
    double lambd = GAMMA_C * linv;

    double Hreg[KH];
    double Eh = 0.0, xold = 0.0;
    __shared__ double yl[KH];
    __shared__ double xl[KH];
    if (lane < KH) {
        if (lane < T36) {
#pragma unroll
            for (int q = 0; q < T36; ++q)
                Hreg[q] = ((lane == q) ? 1.0 : 0.0) - linv * G36[lane * T36 + q];
            Hreg[T36] = -linv * d1v[lane];
            Eh = (lane == t && t < T36) ? linv : 0.0;
        } else {                  // ones-direction passthrough row
#pragma unroll
            for (int q = 0; q < KH; ++q) Hreg[q] = (q == T36) ? 1.0 : 0.0;
            Eh = (t == T36) ? -lambd : 0.0;
        }
        yl[lane] = 0.0;
    } else {
#pragma unroll
        for (int q = 0; q < KH; ++q) Hreg[q] = 0.0;
    }
    __syncthreads();
    double tcur = 1.0;
    for (int n = 0; n < NITER; ++n) {
        // momentum coefficient, bit-matching reference's float32 tts
        double tn = 0.5 * (1.0 + sqrt(1.0 + 4.0 * tcur * tcur));
        double tt = (double)(float)((tcur - 1.0) / tn);
        tcur = tn;
        double a0 = Eh, a1 = 0.0;     // 2 accumulators halve the dependent chain
#pragma unroll
        for (int q = 0; q < T36; q += 2) {
            a0 += Hreg[q] * yl[q];
            a1 += Hreg[q + 1] * yl[q + 1];
        }
        double acc = a0 + a1 + Hreg[T36] * yl[T36];
        __syncthreads();
        double ynew = (1.0 + tt) * acc - tt * xold;
        xold = acc;
        if (lane < KH) yl[lane] = ynew;
        __syncthreads();
    }
    if (lane < KH) xl[lane] = xold;   // x_40 compressed, this block's column
    __syncthreads();
    // expand: Mf[k][t] = sum_s Di[s][k]*xl[s] + xl[36]; lane-consec k -> coalesced
    for (int k = lane; k < K645; k += 64) {
        double acc = xl[T36];
#pragma unroll
        for (int q = 0; q < T36; ++q) acc += Di[q * K645 + k] * xl[q];
        Mf[k * KH + t] = (float)acc;
    }
}

// K4: out[k][p] = sum_t Mf[k][t]*Y[t][p] + Mf[k][36]
__global__ __launch_bounds__(256) void k_out(const float* __restrict__ Y,
                                             const float* __restrict__ Mf,
                                             float* __restrict__ out, int P) {
    int p = blockIdx.x * 256 + threadIdx.x;
    if (p >= P) return;
    int k0 = blockIdx.y * 15;     // 43 chunks * 15 = 645
    float y[T36];
#pragma unroll
    for (int t = 0; t < T36; ++t) y[t] = Y[t * P + p];
    for (int kk = 0; kk < 15; ++kk) {
        int k = k0 + kk;
        const float* m = Mf + k * KH;   // uniform across block -> scalar loads
        float acc = m[T36];
#pragma unroll
        for (int t = 0; t < T36; ++t) acc = fmaf(m[t], y[t], acc);
        out[k * P + p] = acc;
    }
}

extern "C" void kernel_launch(void* const* d_in, const int* in_sizes, int n_in,
                              void* d_out, int out_size, void* d_ws, size_t ws_size,
                              hipStream_t stream) {
    const float* x     = (const float*)d_in[0];   // [1, 36, 8192]
    const float* rr    = (const float*)d_in[1];   // [161]
    const float* theta = (const float*)d_in[2];   // [161]
    float* out = (float*)d_out;                   // [1, 645, 8192]

    double* ws   = (double*)d_ws;                 // needs ~292 KB
    double* Di   = ws;                            // 23220
    double* G36  = ws + 23220;                    // 1296
    double* d1v  = ws + 24516;                    // 36
    float*  Mf   = (float*)(ws + 24552);          // 645*37 floats

    int P = in_sizes[0] / T36;                    // 8192

    k_build<<<dim3((K645 + 255) / 256), dim3(256), 0, stream>>>(rr, theta, Di);
    k_gram<<<dim3(T36, KH), dim3(64), 0, stream>>>(Di, G36, d1v);
    k_solve<<<dim3(KH), dim3(64), 0, stream>>>(Di, G36, d1v, Mf);
    k_out<<<dim3((P + 255) / 256, 43), dim3(256), 0, stream>>>(x, Mf, out, P);
}